// Round 7
// baseline (128.276 us; speedup 1.0000x reference)
//
#include <hip/hip_runtime.h>
#include <hip/hip_fp16.h>
#include <math.h>

#define NUM_VARS 64
#define KK       32
#define NUM_CATS 256
#define LL       4
#define EE       16384
#define NN       8192
#define CC       4
#define BB       1024
#define NUM_INPUT 2048             // NUM_VARS * KK
#define ROWS_LDS  26624            // NUM_INPUT + 3*NN (last layer not stored)
#define THREADS   1024
#define CH       4                 // nodes staged per chunk (ILP depth)
// LDS: 26624 rows x __half2 (4B) + 64 f32 reduce scratch + 128 int cats
#define LDS_FLOATS (ROWS_LDS + 64 + 128)
#define LDS_BYTES  (LDS_FLOATS * 4)

#define LOG2E 1.4426950408889634f
#define LN2   0.6931471805599453f

#if __has_builtin(__builtin_amdgcn_exp2f)
#define EXP2(x) __builtin_amdgcn_exp2f(x)
#else
#define EXP2(x) exp2f(x)
#endif
#if __has_builtin(__builtin_amdgcn_logf)
#define LOG2(x) __builtin_amdgcn_logf(x)
#else
#define LOG2(x) log2f(x)
#endif

// Per-layer magnitude biases (log2 domain). Stored row = true - BIAS[layer].
// All bias algebra is folded into prep-computed weights; kernel never sees it.
#define B_IN  (-9.0f)
#define B_L0  (-19.0f)
#define B_L1  (-39.0f)
#define B_L2  (-79.0f)

__device__ __forceinline__ float child_bias(int row) {
    // layer of a child row: input / L0 / L1 / L2 (layer-3 rows are never children)
    if (row < NUM_INPUT) return B_IN;
    int l = (row - NUM_INPUT) >> 13;
    return l == 0 ? B_L0 : (l == 1 ? B_L1 : B_L2);
}

// ---------------------------------------------------------------------------
// Prep: collapse sum_ch_ids -> prod_ids into 8 LDS byte offsets per node;
// weights -> base-2 domain with child/node biases and root_logw folded in.
// grid: L*N/64 blocks of 64 (spread over all CUs; latency-bound).
// ---------------------------------------------------------------------------
__global__ void prep_kernel(const int* __restrict__ prod_ids,    // L x E x 2
                            const int* __restrict__ sum_ch_ids,  // L x N x C
                            const float* __restrict__ sum_logw,  // L x N x C
                            const float* __restrict__ root_logw, // N
                            int4* __restrict__ recA,             // L*N x 2
                            float4* __restrict__ recB)           // L*N
{
    int idx = blockIdx.x * 64 + threadIdx.x;      // 0 .. L*N-1
    int l = idx >> 13;
    int n = idx & (NN - 1);
    const int*  sch  = sum_ch_ids + (size_t)idx * CC;
    const int2* prod = (const int2*)prod_ids + (size_t)l * EE;
    int2 p0 = prod[sch[0]];
    int2 p1 = prod[sch[1]];
    int2 p2 = prod[sch[2]];
    int2 p3 = prod[sch[3]];
    recA[(size_t)idx * 2]     = make_int4(p0.x << 2, p0.y << 2, p1.x << 2, p1.y << 2);
    recA[(size_t)idx * 2 + 1] = make_int4(p2.x << 2, p2.y << 2, p3.x << 2, p3.y << 2);

    const float nodeB[4] = {B_L0, B_L1, B_L2, 0.0f};
    float r = (l == 3) ? root_logw[n] : 0.0f;
    const float* w = sum_logw + (size_t)idx * CC;
    float4 wb;
    wb.x = (w[0] + r) * LOG2E + child_bias(p0.x) + child_bias(p0.y) - nodeB[l];
    wb.y = (w[1] + r) * LOG2E + child_bias(p1.x) + child_bias(p1.y) - nodeB[l];
    wb.z = (w[2] + r) * LOG2E + child_bias(p2.x) + child_bias(p2.y) - nodeB[l];
    wb.w = (w[3] + r) * LOG2E + child_bias(p3.x) + child_bias(p3.y) - nodeB[l];
    recB[idx] = wb;
}

// base-2 logsumexp of 4 (nested fmax form -> v_max3 fusion)
__device__ __forceinline__ float lse4_2(float a, float b, float c, float d) {
    float m = fmaxf(fmaxf(fmaxf(a, b), c), d);
    float s = EXP2(a - m) + EXP2(b - m) + EXP2(c - m) + EXP2(d - m);
    return m + LOG2(s);
}

__device__ __forceinline__ __half2 ldsh2r(const float* lds, int byteoff) {
    return *(const __half2*)((const char*)lds + byteoff);
}

// ---------------------------------------------------------------------------
// Mega-kernel: one block = TWO batch columns packed as __half2 per row.
// Whole column-pair resident in LDS; compute in f32; base-2 log domain with
// per-layer bias folding (all in prep). Root lse fused.
// Layer loop staged in CH-node chunks: records -> 8*CH independent ds_reads
// -> compute. Static indexing keeps staging in VGPRs.
// ---------------------------------------------------------------------------
__global__ __launch_bounds__(THREADS, 4)
void circuit_kernel(const int* __restrict__ inputs,          // B x NUM_VARS
                    const float* __restrict__ input_logp,    // V x K x CATS
                    const int4* __restrict__ recA,           // L*N x 2
                    const float4* __restrict__ recB,         // L*N
                    float* __restrict__ out)                 // B
{
    extern __shared__ float lds[];
    float* red  = lds + ROWS_LDS;              // 64 floats (16 waves x 4)
    int*   cats = (int*)(lds + ROWS_LDS + 64); // 128 ints (2 cols x 64 vars)
    __half2* rows = (__half2*)lds;

    int b2 = blockIdx.x * 2;                   // first of the 2 batch columns
    int t = threadIdx.x;

    if (t < 128) {
        int col = t >> 6, v = t & 63;
        cats[t] = inputs[(b2 + col) * NUM_VARS + v];
    }
    __syncthreads();

    // ---- input layer: rows[idx] = half2(log2e*logp[idx][catA]-B, ...catB...)
#pragma unroll
    for (int i = 0; i < NUM_INPUT / THREADS; ++i) {
        int idx = t + i * THREADS;
        int v = idx >> 5;
        const float* base = input_logp + (size_t)idx * NUM_CATS;
        float fa = fmaf(base[cats[v]],      LOG2E, -B_IN);
        float fb = fmaf(base[cats[64 + v]], LOG2E, -B_IN);
        rows[idx] = __floats2half2_rn(fa, fb);
    }
    __syncthreads();

    // ---- layers 0..2: store into LDS
    for (int l = 0; l < 3; ++l) {
        const int4*   ra = recA + (size_t)l * NN * 2;
        const float4* rb = recB + (size_t)l * NN;
        __half2* dst = rows + NUM_INPUT + l * NN;
        for (int i = 0; i < NN / THREADS; i += CH) {
            int4 r0[CH], r1[CH];
            float4 w[CH];
#pragma unroll
            for (int j = 0; j < CH; ++j) {
                int n = t + (i + j) * THREADS;
                r0[j] = ra[(size_t)n * 2];
                r1[j] = ra[(size_t)n * 2 + 1];
                w[j]  = rb[n];
            }
            __half2 h[CH][8];
#pragma unroll
            for (int j = 0; j < CH; ++j) {
                h[j][0] = ldsh2r(lds, r0[j].x);
                h[j][1] = ldsh2r(lds, r0[j].y);
                h[j][2] = ldsh2r(lds, r0[j].z);
                h[j][3] = ldsh2r(lds, r0[j].w);
                h[j][4] = ldsh2r(lds, r1[j].x);
                h[j][5] = ldsh2r(lds, r1[j].y);
                h[j][6] = ldsh2r(lds, r1[j].z);
                h[j][7] = ldsh2r(lds, r1[j].w);
            }
#pragma unroll
            for (int j = 0; j < CH; ++j) {
                int n = t + (i + j) * THREADS;
                float2 c0 = __half22float2(h[j][0]), d0 = __half22float2(h[j][1]);
                float2 c1 = __half22float2(h[j][2]), d1 = __half22float2(h[j][3]);
                float2 c2 = __half22float2(h[j][4]), d2 = __half22float2(h[j][5]);
                float2 c3 = __half22float2(h[j][6]), d3 = __half22float2(h[j][7]);
                float xA = lse4_2(w[j].x + c0.x + d0.x, w[j].y + c1.x + d1.x,
                                  w[j].z + c2.x + d2.x, w[j].w + c3.x + d3.x);
                float xB = lse4_2(w[j].x + c0.y + d0.y, w[j].y + c1.y + d1.y,
                                  w[j].z + c2.y + d2.y, w[j].w + c3.y + d3.y);
                dst[n] = __floats2half2_rn(xA, xB);
            }
        }
        __syncthreads();
    }

    // ---- layer 3 + root accumulate (root_logw folded; node bias 0 -> true)
    {
        const int4*   ra = recA + (size_t)3 * NN * 2;
        const float4* rb = recB + (size_t)3 * NN;
        float mA = -INFINITY, sA = 0.0f, mB = -INFINITY, sB = 0.0f;
        for (int i = 0; i < NN / THREADS; i += CH) {
            int4 r0[CH], r1[CH];
            float4 w[CH];
#pragma unroll
            for (int j = 0; j < CH; ++j) {
                int n = t + (i + j) * THREADS;
                r0[j] = ra[(size_t)n * 2];
                r1[j] = ra[(size_t)n * 2 + 1];
                w[j]  = rb[n];
            }
            __half2 h[CH][8];
#pragma unroll
            for (int j = 0; j < CH; ++j) {
                h[j][0] = ldsh2r(lds, r0[j].x);
                h[j][1] = ldsh2r(lds, r0[j].y);
                h[j][2] = ldsh2r(lds, r0[j].z);
                h[j][3] = ldsh2r(lds, r0[j].w);
                h[j][4] = ldsh2r(lds, r1[j].x);
                h[j][5] = ldsh2r(lds, r1[j].y);
                h[j][6] = ldsh2r(lds, r1[j].z);
                h[j][7] = ldsh2r(lds, r1[j].w);
            }
#pragma unroll
            for (int j = 0; j < CH; ++j) {
                float2 c0 = __half22float2(h[j][0]), d0 = __half22float2(h[j][1]);
                float2 c1 = __half22float2(h[j][2]), d1 = __half22float2(h[j][3]);
                float2 c2 = __half22float2(h[j][4]), d2 = __half22float2(h[j][5]);
                float2 c3 = __half22float2(h[j][6]), d3 = __half22float2(h[j][7]);
                float vA = lse4_2(w[j].x + c0.x + d0.x, w[j].y + c1.x + d1.x,
                                  w[j].z + c2.x + d2.x, w[j].w + c3.x + d3.x);
                float vB = lse4_2(w[j].x + c0.y + d0.y, w[j].y + c1.y + d1.y,
                                  w[j].z + c2.y + d2.y, w[j].w + c3.y + d3.y);
                float tA = fmaxf(mA, vA);
                sA = sA * EXP2(mA - tA) + EXP2(vA - tA); mA = tA;
                float tB = fmaxf(mB, vB);
                sB = sB * EXP2(mB - tB) + EXP2(vB - tB); mB = tB;
            }
        }
        // wave reduce (64 lanes), both columns
#pragma unroll
        for (int off = 32; off >= 1; off >>= 1) {
            float omA = __shfl_xor(mA, off), osA = __shfl_xor(sA, off);
            float tA = fmaxf(mA, omA);
            sA = sA * EXP2(mA - tA) + osA * EXP2(omA - tA); mA = tA;
            float omB = __shfl_xor(mB, off), osB = __shfl_xor(sB, off);
            float tB = fmaxf(mB, omB);
            sB = sB * EXP2(mB - tB) + osB * EXP2(omB - tB); mB = tB;
        }
        int wid = t >> 6;
        if ((t & 63) == 0) {
            red[wid * 4]     = mA; red[wid * 4 + 1] = sA;
            red[wid * 4 + 2] = mB; red[wid * 4 + 3] = sB;
        }
        __syncthreads();
        if (t == 0) {
            float MA = -INFINITY, MB = -INFINITY;
#pragma unroll
            for (int wv = 0; wv < THREADS / 64; ++wv) {
                MA = fmaxf(MA, red[wv * 4]);
                MB = fmaxf(MB, red[wv * 4 + 2]);
            }
            float SA = 0.0f, SB = 0.0f;
#pragma unroll
            for (int wv = 0; wv < THREADS / 64; ++wv) {
                SA += red[wv * 4 + 1] * EXP2(red[wv * 4]     - MA);
                SB += red[wv * 4 + 3] * EXP2(red[wv * 4 + 2] - MB);
            }
            out[b2]     = (MA + LOG2(SA)) * LN2;
            out[b2 + 1] = (MB + LOG2(SB)) * LN2;
        }
    }
}

extern "C" void kernel_launch(void* const* d_in, const int* in_sizes, int n_in,
                              void* d_out, int out_size, void* d_ws, size_t ws_size,
                              hipStream_t stream) {
    const int*   inputs      = (const int*)d_in[0];
    const float* input_logp  = (const float*)d_in[1];
    const int*   prod_ids    = (const int*)d_in[2];
    const int*   sum_ch_ids  = (const int*)d_in[3];
    const float* sum_logw    = (const float*)d_in[4];
    const float* root_logw   = (const float*)d_in[5];
    float* out = (float*)d_out;

    int4*   recA = (int4*)d_ws;                           // [L*N][2] int4
    float4* recB = (float4*)(recA + (size_t)LL * NN * 2); // [L*N] float4

    static bool attr_done = false;
    if (!attr_done) {
        hipFuncSetAttribute((const void*)circuit_kernel,
                            hipFuncAttributeMaxDynamicSharedMemorySize, LDS_BYTES);
        attr_done = true;
    }

    prep_kernel<<<(LL * NN) / 64, 64, 0, stream>>>(
        prod_ids, sum_ch_ids, sum_logw, root_logw, recA, recB);

    circuit_kernel<<<BB / 2, THREADS, LDS_BYTES, stream>>>(
        inputs, input_logp, recA, recB, out);
}